// Round 9
// baseline (280.938 us; speedup 1.0000x reference)
//
#include <hip/hip_runtime.h>
#include <math.h>

#define BB 16
#define QQ 900
#define CC 91
#define TT 100
#define BT (BB * TT)                    // 1600
#define NTHREADS 256
#define TILE 15                         // query rows per cost block
#define NBLK_PER_IMG (QQ / TILE)        // 60
#define COST_BLOCKS (BB * NBLK_PER_IMG) // 960
#define NSLOT 15                        // ceil(900/64) row slots per lane
#define WSCOLS 128                      // u64 workspace slots per image
#define PENDK 8                         // pending-buffer slots
#define RB 5                            // row register-block (15 = 3 passes)
#define DONE_TGT 0xFFFFFFC3u            // 0xFFFFFFFF - 60 (countdown target)
#define DONE_OFF ((size_t)BB * WSCOLS * 8)   // done[] starts after colmin (16384 B)

__device__ __forceinline__ unsigned ordkey(float f) {
    unsigned u = __float_as_uint(f);
    return (u & 0x80000000u) ? ~u : (u | 0x80000000u);
}
__device__ __forceinline__ unsigned long long u64min(unsigned long long a, unsigned long long b) {
    return a < b ? a : b;
}
__device__ __forceinline__ unsigned long long u64max(unsigned long long a, unsigned long long b) {
    return a > b ? a : b;
}
// pack (key,row,col) -> u64; lexicographic == numpy flat-index argmin order
__device__ __forceinline__ unsigned long long packkrc(unsigned key, int row, int col) {
    return ((unsigned long long)key << 21) | ((unsigned long long)row << 11) | (unsigned)col;
}
__device__ __forceinline__ unsigned long long rdlane64(unsigned long long v, int l) {
    unsigned lo = (unsigned)__builtin_amdgcn_readlane((int)(unsigned)v, l);
    unsigned hi = (unsigned)__builtin_amdgcn_readlane((int)(unsigned)(v >> 32), l);
    return ((unsigned long long)hi << 32) | lo;
}

struct SmCost {
    float4 t[BT];           // 25.6 KB AoS targets
    int    lab[BT];         // 6.4 KB
    float  sig[TILE][CC];   // 5.46 KB
    float  row[TILE][8];    // px,py,pz,pw,x0,y0,x1,y1
};
struct SmGreedy {
    unsigned fr[1024];      // first-rank-per-row table (one-time)
    unsigned dead32[256];   // 1024 B row-dead flags (monotonic)
};
union SmAll { SmCost c; SmGreedy g; };

// cooperative rescan of column cc over alive rows.
// AGENT-scope relaxed atomic loads bypass the local XCD L2 -> read LLC-fresh
// cost lines flushed by the writers' __threadfence(). (R4-verified protocol.)
__device__ __forceinline__ unsigned long long rescan_col(
    const float* __restrict__ cb, const unsigned char* s_dead, int cc, int lane)
{
    unsigned long long best = ~0ULL;
    #pragma unroll
    for (int i = 0; i < NSLOT; ++i) {
        int r = i * 64 + lane;
        if (r < QQ && s_dead[r] == 0) {
            float v = __hip_atomic_load(cb + (size_t)r * BT + cc,
                                        __ATOMIC_RELAXED, __HIP_MEMORY_SCOPE_AGENT);
            best = u64min(best, packkrc(ordkey(v), r, cc));
        }
    }
    #pragma unroll
    for (int off = 1; off < 64; off <<= 1)
        best = u64min(best, __shfl_xor(best, off, 64));
    return best;
}

// ---------------------------------------------------------------------------
// Fused kernel (R4-verified structure, spin-protocol fixed):
//   blocks [0,960): cost tiles (bit-exact math) + device atomicMin colmin
//                   + __threadfence release + atomicSub(done[b])
//   blocks [960,976): greedy, RELAXED-poll done[b] (no per-poll buffer_inv
//                   -- R4's storm), ONE acquire load on exit, then the
//                   R7-verified sorted lazy-deletion walk with bulk pops.
// Greedy(image b) overlaps cost(images > b) at boosted clocks -- the 74 us
// idle-clock serial tail hides under the cost phase.
// ---------------------------------------------------------------------------
__global__ __launch_bounds__(NTHREADS, 4) void fused_kernel(
    const float* __restrict__ logits,
    const float* __restrict__ pred,
    const int*   __restrict__ tlab,
    const float* __restrict__ tbox,
    float*       __restrict__ cost,
    unsigned long long* __restrict__ colmin,
    unsigned*    __restrict__ done,
    float*       __restrict__ rows_out,
    float*       __restrict__ cols_out)
{
    __shared__ SmAll sm;
    const int bid = blockIdx.x;

    if (bid < COST_BLOCKS) {
        // =================== COST ROLE (R7-verified math) ===================
        const int b  = bid / NBLK_PER_IMG;
        const int tb = bid % NBLK_PER_IMG;
        const int r0 = tb * TILE;

        for (int j = threadIdx.x; j < BT; j += NTHREADS) {
            sm.c.t[j]   = *(const float4*)(tbox + (size_t)j * 4);
            sm.c.lab[j] = tlab[j];
        }
        for (int u = threadIdx.x; u < TILE * CC; u += NTHREADS) {
            int r = u / CC, c = u % CC;
            float x = logits[((size_t)(b * QQ + r0 + r)) * CC + c];
            sm.c.sig[r][c] = 1.0f / (1.0f + expf(-x));
        }
        if (threadIdx.x < TILE) {
            int r = threadIdx.x;
            const float4 p = *(const float4*)(pred + ((size_t)(b * QQ + r0 + r)) * 4);
            sm.c.row[r][0] = p.x; sm.c.row[r][1] = p.y;
            sm.c.row[r][2] = p.z; sm.c.row[r][3] = p.w;
            sm.c.row[r][4] = p.x - 0.5f * p.z;
            sm.c.row[r][5] = p.y - 0.5f * p.w;
            sm.c.row[r][6] = p.x + 0.5f * p.z;
            sm.c.row[r][7] = p.y + 0.5f * p.w;
        }
        __syncthreads();

        unsigned long long bestc = ~0ULL;   // column-min for col==threadIdx.x (<100)

        for (int p0 = 0; p0 < TILE; p0 += RB) {
            float qx[RB], qy[RB], qz[RB], qw[RB];
            float qx0[RB], qy0[RB], qx1[RB], qy1[RB], qa1[RB];
            #pragma unroll
            for (int rr = 0; rr < RB; ++rr) {
                const int r = p0 + rr;
                qx[rr]  = sm.c.row[r][0]; qy[rr]  = sm.c.row[r][1];
                qz[rr]  = sm.c.row[r][2]; qw[rr]  = sm.c.row[r][3];
                qx0[rr] = sm.c.row[r][4]; qy0[rr] = sm.c.row[r][5];
                qx1[rr] = sm.c.row[r][6]; qy1[rr] = sm.c.row[r][7];
                qa1[rr] = (qx1[rr] - qx0[rr]) * (qy1[rr] - qy0[rr]);
            }
            for (int j = threadIdx.x; j < BT; j += NTHREADS) {
                float4 t = sm.c.t[j];
                int id = sm.c.lab[j];
                float t_x0 = t.x - 0.5f * t.z, t_y0 = t.y - 0.5f * t.w;
                float t_x1 = t.x + 0.5f * t.z, t_y1 = t.y + 0.5f * t.w;
                float area2 = (t_x1 - t_x0) * (t_y1 - t_y0);
                #pragma unroll
                for (int rr = 0; rr < RB; ++rr) {
                    float cclass = -sm.c.sig[p0 + rr][id];
                    float cbbox = ((fabsf(qx[rr] - t.x) + fabsf(qy[rr] - t.y))
                                 + fabsf(qz[rr] - t.z)) + fabsf(qw[rr] - t.w);

                    float ltx = fmaxf(qx0[rr], t_x0), lty = fmaxf(qy0[rr], t_y0);
                    float rbx = fminf(qx1[rr], t_x1), rby = fminf(qy1[rr], t_y1);
                    float iw = fmaxf(rbx - ltx, 0.0f), ih = fmaxf(rby - lty, 0.0f);
                    float inter = iw * ih;
                    float uni = (qa1[rr] + area2) - inter;
                    float iou = inter / uni;

                    float ex0 = fminf(qx0[rr], t_x0), ey0 = fminf(qy0[rr], t_y0);
                    float ex1 = fmaxf(qx1[rr], t_x1), ey1 = fmaxf(qy1[rr], t_y1);
                    float ew = fmaxf(ex1 - ex0, 0.0f), eh = fmaxf(ey1 - ey0, 0.0f);
                    float ae = ew * eh;
                    float giou = iou - (ae - uni) / ae;

                    float v = (cbbox + cclass) + (-giou);
                    cost[((size_t)(b * QQ + r0 + p0 + rr)) * BT + j] = v;
                    if (j < TT)
                        bestc = u64min(bestc, packkrc(ordkey(v), r0 + p0 + rr, j));
                }
            }
        }

        if (threadIdx.x < TT)
            atomicMin(colmin + (size_t)b * WSCOLS + threadIdx.x, bestc);
        __threadfence();                    // flush cost + colmin to LLC
        __syncthreads();                    // all threads fenced before signal
        if (threadIdx.x == 0)
            atomicSub(done + (size_t)b * 16, 1u);   // 64B-strided counter
        return;
    }

    // =================== GREEDY ROLE (blocks 960..975, wave 0) ===================
    const int b = bid - COST_BLOCKS;
    if (threadIdx.x >= 64) return;          // single wave; no barriers below
    const int lane = threadIdx.x;
    const float* cb = cost + (size_t)b * QQ * BT;
    unsigned char* s_dead = (unsigned char*)sm.g.dead32;

    #pragma unroll
    for (int k = 0; k < 16; ++k) sm.g.fr[lane + 64 * k] = 0xFFFFFFFFu;
    #pragma unroll
    for (int k = 0; k < 4; ++k) sm.g.dead32[lane + 64 * k] = 0u;

    // ---- RELAXED spin (no per-poll invalidate); ONE acquire load on exit ----
    {
        const unsigned* dp = done + (size_t)b * 16;
        while (__hip_atomic_load(dp, __ATOMIC_RELAXED, __HIP_MEMORY_SCOPE_AGENT) != DONE_TGT)
            __builtin_amdgcn_s_sleep(8);
        // single acquire (emits one buffer_inv, not one per poll -- R4's bug)
        (void)__hip_atomic_load(dp, __ATOMIC_ACQUIRE, __HIP_MEMORY_SCOPE_AGENT);
    }

    // ---- load 100 column minima (AGENT relaxed: LLC-fresh) ----
    unsigned long long va = __hip_atomic_load(colmin + (size_t)b * WSCOLS + lane,
                                              __ATOMIC_RELAXED, __HIP_MEMORY_SCOPE_AGENT);
    unsigned long long vb = (lane < TT - 64)
        ? __hip_atomic_load(colmin + (size_t)b * WSCOLS + 64 + lane,
                            __ATOMIC_RELAXED, __HIP_MEMORY_SCOPE_AGENT)
        : ~0ULL;

    // ---- bitonic sort, 128 elements across 64 lanes x 2 regs, ascending ----
    #pragma unroll
    for (int k = 2; k <= 128; k <<= 1) {
        #pragma unroll
        for (int j = k >> 1; j > 0; j >>= 1) {
            if (j == 64) {
                unsigned long long lo = u64min(va, vb);
                unsigned long long hi = va ^ vb ^ lo;
                va = lo; vb = hi;
            } else {
                unsigned long long pa = __shfl_xor(va, j, 64);
                bool ta = ((lane & j) == 0) == ((lane & k) == 0);
                va = ta ? u64min(va, pa) : u64max(va, pa);
                unsigned long long pb = __shfl_xor(vb, j, 64);
                int ib = lane + 64;
                bool tb_ = ((ib & j) == 0) == ((ib & k) == 0);
                vb = tb_ ? u64min(vb, pb) : u64max(vb, pb);
            }
        }
    }

    const int rA = (int)((va >> 11) & 0x3FF);
    const int cA = (int)(va & 0x7FF);
    const int rB = (int)((vb >> 11) & 0x3FF);
    const int cB = (int)(vb & 0x7FF);

    // ---- one-time firstdup: smallest earlier rank with same row ----
    atomicMin(&sm.g.fr[rA], (unsigned)lane);
    atomicMin(&sm.g.fr[rB], (unsigned)(64 + lane));
    __threadfence_block();
    unsigned frA = sm.g.fr[rA], frB = sm.g.fr[rB];
    const unsigned fdA = (frA < (unsigned)lane)        ? frA : 0xFFFFFFFFu;
    const unsigned fdB = (frB < (unsigned)(64 + lane)) ? frB : 0xFFFFFFFFu;

    // ---- round loop: light bulk-pops + rare events (R7-verified) ----
    unsigned long long pend[PENDK];
    #pragma unroll
    for (int t = 0; t < PENDK; ++t) pend[t] = ~0ULL;
    unsigned long long pmin = ~0ULL;

    int cur = 0, m = 0, guard = 0;
    while (m < TT && ++guard < 2048) {
        __threadfence_block();
        bool dA = s_dead[rA] != 0;
        bool dB = s_dead[rB] != 0;

        bool evA = (lane >= cur) &&
                   (dA || (fdA != 0xFFFFFFFFu && fdA >= (unsigned)cur) || (pmin < va));
        bool evB = ((64 + lane) >= cur) &&
                   (dB || (fdB != 0xFFFFFFFFu && fdB >= (unsigned)cur) || (pmin < vb));
        unsigned long long mA = __ballot(evA);
        unsigned long long mB = __ballot(evB);
        int k = mA ? (int)__ffsll(mA) - 1
              : (mB ? 64 + (int)__ffsll(mB) - 1 : 128);

        int n = k - cur;
        if (n > TT - m) n = TT - m;
        if (n > 0) {
            // bulk match ranks [cur, cur+n): alive, unique rows
            int iA = lane - cur;
            if (iA >= 0 && iA < n) {
                rows_out[b * TT + m + iA] = (float)rA;
                cols_out[b * TT + m + iA] = (float)cA;
                s_dead[rA] = 1;
            }
            int iB = 64 + lane - cur;
            if (iB >= 0 && iB < n) {
                rows_out[b * TT + m + iB] = (float)rB;
                cols_out[b * TT + m + iB] = (float)cB;
                s_dead[rB] = 1;
            }
            m += n; cur += n;
            if (m >= TT) break;
        }

        // ---- single event at rank cur ----
        unsigned long long ecur = (cur < 64) ? rdlane64(va, cur)
                                : (cur < 128) ? rdlane64(vb, cur - 64) : ~0ULL;
        __threadfence_block();

        if (pmin < ecur) {
            // pop pending entry
            unsigned long long e = pmin;
            bool removed = false;
            #pragma unroll
            for (int t = 0; t < PENDK; ++t)
                if (!removed && pend[t] == e) { pend[t] = ~0ULL; removed = true; }
            pmin = ~0ULL;
            #pragma unroll
            for (int t = 0; t < PENDK; ++t) pmin = u64min(pmin, pend[t]);

            int re = (int)((e >> 11) & 0x3FF);
            int ce = (int)(e & 0x7FF);
            bool alive = (s_dead[re] == 0);    // same-addr broadcast read
            if (alive) {
                if (lane == 0) {
                    rows_out[b * TT + m] = (float)re;
                    cols_out[b * TT + m] = (float)ce;
                    s_dead[re] = 1;
                }
                ++m;
            } else {
                unsigned long long best = rescan_col(cb, s_dead, ce, lane);
                bool placed = false;
                #pragma unroll
                for (int t = 0; t < PENDK; ++t)
                    if (!placed && pend[t] == ~0ULL) { pend[t] = best; placed = true; }
                pmin = u64min(pmin, best);
            }
        } else if (cur < 128) {
            // sorted entry at cur is stale (row dead): rescan its column
            int ccur = (int)(ecur & 0x7FF);
            unsigned long long best = rescan_col(cb, s_dead, ccur, lane);
            bool placed = false;
            #pragma unroll
            for (int t = 0; t < PENDK; ++t)
                if (!placed && pend[t] == ~0ULL) { pend[t] = best; placed = true; }
            pmin = u64min(pmin, best);
            ++cur;
        }
    }
}

extern "C" void kernel_launch(void* const* d_in, const int* in_sizes, int n_in,
                              void* d_out, int out_size, void* d_ws, size_t ws_size,
                              hipStream_t stream) {
    const float* logits = (const float*)d_in[0];   // [16,900,91]
    const float* pred   = (const float*)d_in[1];   // [16,900,4]
    const int*   tlab   = (const int*)d_in[2];     // [16,100]
    const float* tbox   = (const float*)d_in[3];   // [16,100,4]

    float* out = (float*)d_out;
    float* cost = out;                              // 23,040,000
    float* rows = out + (size_t)BB * QQ * BT;       // 1600
    float* cols = rows + (size_t)BB * TT;           // 1600

    unsigned long long* colmin = (unsigned long long*)d_ws;        // 16 KB
    unsigned* done = (unsigned*)((char*)d_ws + DONE_OFF);          // 16 x 64 B

    // 0xFF-fill: colmin sentinels (~0ULL) + done countdown start (0xFFFFFFFF)
    (void)hipMemsetAsync(d_ws, 0xFF, DONE_OFF + (size_t)BB * 64, stream);

    fused_kernel<<<COST_BLOCKS + BB, NTHREADS, 0, stream>>>(
        logits, pred, tlab, tbox, cost, colmin, done, rows, cols);
}

// Round 10
// 237.605 us; speedup vs baseline: 1.1824x; 1.1824x over previous
//
#include <hip/hip_runtime.h>
#include <math.h>

#define BB 16
#define QQ 900
#define CC 91
#define TT 100
#define BT (BB * TT)                    // 1600
#define NTHREADS 512
#define TILE 15                         // query rows per cost tile
#define NBLK_PER_IMG (QQ / TILE)        // 60
#define COST_BLOCKS 240                 // x 4 passes = 960 tiles
#define NPASS 4                         // images per pass = 4
#define GRID (COST_BLOCKS + BB)         // 256 = 1 block/CU
#define NSLOT 15                        // ceil(900/64) row slots per lane
#define PENDK 8                         // pending-buffer slots
#define RB 5                            // row register-block (15 = 3 passes)
#define SLOTS_BYTES ((size_t)BB * NBLK_PER_IMG * TT * 8)   // 768000
#define DONE_OFF SLOTS_BYTES

__device__ __forceinline__ unsigned ordkey(float f) {
    unsigned u = __float_as_uint(f);
    return (u & 0x80000000u) ? ~u : (u | 0x80000000u);
}
__device__ __forceinline__ unsigned long long u64min(unsigned long long a, unsigned long long b) {
    return a < b ? a : b;
}
__device__ __forceinline__ unsigned long long u64max(unsigned long long a, unsigned long long b) {
    return a > b ? a : b;
}
// pack (key,row,col) -> u64; lexicographic == numpy flat-index argmin order
__device__ __forceinline__ unsigned long long packkrc(unsigned key, int row, int col) {
    return ((unsigned long long)key << 21) | ((unsigned long long)row << 11) | (unsigned)col;
}
__device__ __forceinline__ unsigned long long rdlane64(unsigned long long v, int l) {
    unsigned lo = (unsigned)__builtin_amdgcn_readlane((int)(unsigned)v, l);
    unsigned hi = (unsigned)__builtin_amdgcn_readlane((int)(unsigned)(v >> 32), l);
    return ((unsigned long long)hi << 32) | lo;
}

struct SmCost {
    float4 t[BT];           // 25.6 KB AoS targets (image-0 cols used by matcher; all for cost)
    int    lab[BT];         // 6.4 KB
    float  sig[TILE][CC];   // per-pass tile sigmoids
    float  row[TILE][8];    // px,py,pz,pw,x0,y0,x1,y1
};
struct SmGreedy {
    unsigned fr[1024];      // first-rank-per-row table (one-time)
    unsigned dead32[256];   // 1024 B row-dead flags (monotonic)
};
union SmAll { SmCost c; SmGreedy g; };

// Rescan of column cc for image b, RECOMPUTED from read-only inputs --
// bit-identical expression tree to the cost role, so the matcher ordering
// is unchanged. No dependence on the cost matrix -> no coherence protocol.
__device__ __forceinline__ unsigned long long rescan_recompute(
    const float* __restrict__ logits, const float* __restrict__ pred,
    int b, const unsigned char* s_dead, int cc, float4 t, int id, int lane)
{
    float t_x0 = t.x - 0.5f * t.z, t_y0 = t.y - 0.5f * t.w;
    float t_x1 = t.x + 0.5f * t.z, t_y1 = t.y + 0.5f * t.w;
    float area2 = (t_x1 - t_x0) * (t_y1 - t_y0);

    unsigned long long best = ~0ULL;
    #pragma unroll
    for (int i = 0; i < NSLOT; ++i) {
        int r = i * 64 + lane;
        if (r < QQ && s_dead[r] == 0) {
            float4 p = *(const float4*)(pred + ((size_t)(b * QQ + r)) * 4);
            float x = logits[((size_t)(b * QQ + r)) * CC + id];
            float cclass = -(1.0f / (1.0f + expf(-x)));
            float cbbox = ((fabsf(p.x - t.x) + fabsf(p.y - t.y))
                         + fabsf(p.z - t.z)) + fabsf(p.w - t.w);

            float p_x0 = p.x - 0.5f * p.z, p_y0 = p.y - 0.5f * p.w;
            float p_x1 = p.x + 0.5f * p.z, p_y1 = p.y + 0.5f * p.w;
            float area1 = (p_x1 - p_x0) * (p_y1 - p_y0);

            float ltx = fmaxf(p_x0, t_x0), lty = fmaxf(p_y0, t_y0);
            float rbx = fminf(p_x1, t_x1), rby = fminf(p_y1, t_y1);
            float iw = fmaxf(rbx - ltx, 0.0f), ih = fmaxf(rby - lty, 0.0f);
            float inter = iw * ih;
            float uni = (area1 + area2) - inter;
            float iou = inter / uni;

            float ex0 = fminf(p_x0, t_x0), ey0 = fminf(p_y0, t_y0);
            float ex1 = fmaxf(p_x1, t_x1), ey1 = fmaxf(p_y1, t_y1);
            float ew = fmaxf(ex1 - ex0, 0.0f), eh = fmaxf(ey1 - ey0, 0.0f);
            float ae = ew * eh;
            float giou = iou - (ae - uni) / ae;

            float v = (cbbox + cclass) + (-giou);
            best = u64min(best, packkrc(ordkey(v), r, cc));
        }
    }
    #pragma unroll
    for (int off = 1; off < 64; off <<= 1)
        best = u64min(best, __shfl_xor(best, off, 64));
    return best;
}

// ---------------------------------------------------------------------------
// Fused pipelined kernel, 256 blocks (1/CU):
//  blocks [0,240): 4 passes; pass p computes tile (bid%60) of image 4p+bid/60.
//    Cost stores are NONTEMPORAL (no dirty L2 -> no threadfence storm, the
//    R4/R9 199us suspect). Column minima -> agent-scope slot stores (LLC),
//    then plain atomicAdd(done[img]) after a vmcnt-draining barrier.
//  blocks [240,256): greedy for image bid-240. Relaxed spin on done==60
//    (R9-verified), one acquire load, agent-load slots, then the R7-verified
//    sorted lazy-deletion walk; rescans recompute from inputs.
//  Image 0 is released after ~1/4 of the cost phase -> greedy walks run at
//  boosted clock under the remaining passes; only the last 4 images' tails
//  are exposed.
// ---------------------------------------------------------------------------
__global__ __launch_bounds__(NTHREADS, 1) void fused_kernel(
    const float* __restrict__ logits,
    const float* __restrict__ pred,
    const int*   __restrict__ tlab,
    const float* __restrict__ tbox,
    float*       __restrict__ cost,
    unsigned long long* __restrict__ slots,
    unsigned*    __restrict__ done,
    float*       __restrict__ rows_out,
    float*       __restrict__ cols_out)
{
    __shared__ SmAll sm;
    const int bid = blockIdx.x;

    if (bid < COST_BLOCKS) {
        // =================== COST ROLE ===================
        const int g  = bid / NBLK_PER_IMG;        // image-group 0..3
        const int tb = bid % NBLK_PER_IMG;        // tile in image
        const int r0 = tb * TILE;

        // stage targets once (same for every pass)
        for (int j = threadIdx.x; j < BT; j += NTHREADS) {
            sm.c.t[j]   = *(const float4*)(tbox + (size_t)j * 4);
            sm.c.lab[j] = tlab[j];
        }

        for (int p = 0; p < NPASS; ++p) {
            const int b = NPASS * p + g;          // wait: see note below

            // NOTE: image ordering — pass p must release images 4p..4p+3.
            // With b = 4p + g, pass 0 covers images 0..3. (g spans 0..3.)
            const int img = 4 * p + g;
            (void)b;

            // per-pass tile staging
            for (int u = threadIdx.x; u < TILE * CC; u += NTHREADS) {
                int r = u / CC, c = u % CC;
                float x = logits[((size_t)(img * QQ + r0 + r)) * CC + c];
                sm.c.sig[r][c] = 1.0f / (1.0f + expf(-x));
            }
            if (threadIdx.x < TILE) {
                int r = threadIdx.x;
                const float4 pp = *(const float4*)(pred + ((size_t)(img * QQ + r0 + r)) * 4);
                sm.c.row[r][0] = pp.x; sm.c.row[r][1] = pp.y;
                sm.c.row[r][2] = pp.z; sm.c.row[r][3] = pp.w;
                sm.c.row[r][4] = pp.x - 0.5f * pp.z;
                sm.c.row[r][5] = pp.y - 0.5f * pp.w;
                sm.c.row[r][6] = pp.x + 0.5f * pp.z;
                sm.c.row[r][7] = pp.y + 0.5f * pp.w;
            }
            __syncthreads();                       // staging visible

            unsigned long long bestc = ~0ULL;      // col-min for col==tid (<100)

            for (int p0 = 0; p0 < TILE; p0 += RB) {
                float qx[RB], qy[RB], qz[RB], qw[RB];
                float qx0[RB], qy0[RB], qx1[RB], qy1[RB], qa1[RB];
                #pragma unroll
                for (int rr = 0; rr < RB; ++rr) {
                    const int r = p0 + rr;
                    qx[rr]  = sm.c.row[r][0]; qy[rr]  = sm.c.row[r][1];
                    qz[rr]  = sm.c.row[r][2]; qw[rr]  = sm.c.row[r][3];
                    qx0[rr] = sm.c.row[r][4]; qy0[rr] = sm.c.row[r][5];
                    qx1[rr] = sm.c.row[r][6]; qy1[rr] = sm.c.row[r][7];
                    qa1[rr] = (qx1[rr] - qx0[rr]) * (qy1[rr] - qy0[rr]);
                }
                for (int j = threadIdx.x; j < BT; j += NTHREADS) {
                    float4 t = sm.c.t[j];
                    int id = sm.c.lab[j];
                    float t_x0 = t.x - 0.5f * t.z, t_y0 = t.y - 0.5f * t.w;
                    float t_x1 = t.x + 0.5f * t.z, t_y1 = t.y + 0.5f * t.w;
                    float area2 = (t_x1 - t_x0) * (t_y1 - t_y0);
                    #pragma unroll
                    for (int rr = 0; rr < RB; ++rr) {
                        float cclass = -sm.c.sig[p0 + rr][id];
                        float cbbox = ((fabsf(qx[rr] - t.x) + fabsf(qy[rr] - t.y))
                                     + fabsf(qz[rr] - t.z)) + fabsf(qw[rr] - t.w);

                        float ltx = fmaxf(qx0[rr], t_x0), lty = fmaxf(qy0[rr], t_y0);
                        float rbx = fminf(qx1[rr], t_x1), rby = fminf(qy1[rr], t_y1);
                        float iw = fmaxf(rbx - ltx, 0.0f), ih = fmaxf(rby - lty, 0.0f);
                        float inter = iw * ih;
                        float uni = (qa1[rr] + area2) - inter;
                        float iou = inter / uni;

                        float ex0 = fminf(qx0[rr], t_x0), ey0 = fminf(qy0[rr], t_y0);
                        float ex1 = fmaxf(qx1[rr], t_x1), ey1 = fmaxf(qy1[rr], t_y1);
                        float ew = fmaxf(ex1 - ex0, 0.0f), eh = fmaxf(ey1 - ey0, 0.0f);
                        float ae = ew * eh;
                        float giou = iou - (ae - uni) / ae;

                        float v = (cbbox + cclass) + (-giou);
                        __builtin_nontemporal_store(
                            v, &cost[((size_t)(img * QQ + r0 + p0 + rr)) * BT + j]);
                        if (j < TT)
                            bestc = u64min(bestc, packkrc(ordkey(v), r0 + p0 + rr, j));
                    }
                }
            }
            __syncthreads();                       // compute done (s_sig reads finished)

            if (threadIdx.x < TT)
                __hip_atomic_store(
                    slots + ((size_t)(img * NBLK_PER_IMG) + tb) * TT + threadIdx.x,
                    bestc, __ATOMIC_RELAXED, __HIP_MEMORY_SCOPE_AGENT);
            __syncthreads();                       // vmcnt drained: slots at LLC
            if (threadIdx.x == 0)
                atomicAdd(done + (size_t)img * 16, 1u);   // device-scope signal
        }
        return;
    }

    // =================== GREEDY ROLE (blocks 240..255, wave 0) ===================
    const int b = bid - COST_BLOCKS;
    if (threadIdx.x >= 64) return;          // single wave; no barriers below
    const int lane = threadIdx.x;
    unsigned char* s_dead = (unsigned char*)sm.g.dead32;

    #pragma unroll
    for (int k = 0; k < 16; ++k) sm.g.fr[lane + 64 * k] = 0xFFFFFFFFu;
    #pragma unroll
    for (int k = 0; k < 4; ++k) sm.g.dead32[lane + 64 * k] = 0u;

    // ---- relaxed spin until this image's 60 tiles signaled; one acquire ----
    {
        const unsigned* dp = done + (size_t)b * 16;
        while (__hip_atomic_load(dp, __ATOMIC_RELAXED, __HIP_MEMORY_SCOPE_AGENT)
               != (unsigned)NBLK_PER_IMG)
            __builtin_amdgcn_s_sleep(8);
        (void)__hip_atomic_load(dp, __ATOMIC_ACQUIRE, __HIP_MEMORY_SCOPE_AGENT);
    }

    // ---- reduce 60 slots -> column minima (agent loads: LLC-fresh) ----
    const unsigned long long* sb = slots + (size_t)b * NBLK_PER_IMG * TT;
    unsigned long long va = ~0ULL, vb = ~0ULL;
    #pragma unroll 6
    for (int t = 0; t < NBLK_PER_IMG; ++t) {
        va = u64min(va, __hip_atomic_load(sb + (size_t)t * TT + lane,
                                          __ATOMIC_RELAXED, __HIP_MEMORY_SCOPE_AGENT));
        if (lane < TT - 64)
            vb = u64min(vb, __hip_atomic_load(sb + (size_t)t * TT + 64 + lane,
                                              __ATOMIC_RELAXED, __HIP_MEMORY_SCOPE_AGENT));
    }

    // ---- bitonic sort, 128 elements across 64 lanes x 2 regs, ascending ----
    #pragma unroll
    for (int k = 2; k <= 128; k <<= 1) {
        #pragma unroll
        for (int j = k >> 1; j > 0; j >>= 1) {
            if (j == 64) {
                unsigned long long lo = u64min(va, vb);
                unsigned long long hi = va ^ vb ^ lo;
                va = lo; vb = hi;
            } else {
                unsigned long long pa = __shfl_xor(va, j, 64);
                bool ta = ((lane & j) == 0) == ((lane & k) == 0);
                va = ta ? u64min(va, pa) : u64max(va, pa);
                unsigned long long pb = __shfl_xor(vb, j, 64);
                int ib = lane + 64;
                bool tb_ = ((ib & j) == 0) == ((ib & k) == 0);
                vb = tb_ ? u64min(vb, pb) : u64max(vb, pb);
            }
        }
    }

    const int rA = (int)((va >> 11) & 0x3FF);
    const int cA = (int)(va & 0x7FF);
    const int rB = (int)((vb >> 11) & 0x3FF);
    const int cB = (int)(vb & 0x7FF);

    // ---- one-time firstdup: smallest earlier rank with same row ----
    atomicMin(&sm.g.fr[rA], (unsigned)lane);
    atomicMin(&sm.g.fr[rB], (unsigned)(64 + lane));
    __threadfence_block();
    unsigned frA = sm.g.fr[rA], frB = sm.g.fr[rB];
    const unsigned fdA = (frA < (unsigned)lane)        ? frA : 0xFFFFFFFFu;
    const unsigned fdB = (frB < (unsigned)(64 + lane)) ? frB : 0xFFFFFFFFu;

    // ---- round loop: light bulk-pops + rare events (R7-verified) ----
    unsigned long long pend[PENDK];
    #pragma unroll
    for (int t = 0; t < PENDK; ++t) pend[t] = ~0ULL;
    unsigned long long pmin = ~0ULL;

    int cur = 0, m = 0, guard = 0;
    while (m < TT && ++guard < 2048) {
        __threadfence_block();
        bool dA = s_dead[rA] != 0;
        bool dB = s_dead[rB] != 0;

        bool evA = (lane >= cur) &&
                   (dA || (fdA != 0xFFFFFFFFu && fdA >= (unsigned)cur) || (pmin < va));
        bool evB = ((64 + lane) >= cur) &&
                   (dB || (fdB != 0xFFFFFFFFu && fdB >= (unsigned)cur) || (pmin < vb));
        unsigned long long mA = __ballot(evA);
        unsigned long long mB = __ballot(evB);
        int k = mA ? (int)__ffsll(mA) - 1
              : (mB ? 64 + (int)__ffsll(mB) - 1 : 128);

        int n = k - cur;
        if (n > TT - m) n = TT - m;
        if (n > 0) {
            int iA = lane - cur;
            if (iA >= 0 && iA < n) {
                rows_out[b * TT + m + iA] = (float)rA;
                cols_out[b * TT + m + iA] = (float)cA;
                s_dead[rA] = 1;
            }
            int iB = 64 + lane - cur;
            if (iB >= 0 && iB < n) {
                rows_out[b * TT + m + iB] = (float)rB;
                cols_out[b * TT + m + iB] = (float)cB;
                s_dead[rB] = 1;
            }
            m += n; cur += n;
            if (m >= TT) break;
        }

        // ---- single event at rank cur ----
        unsigned long long ecur = (cur < 64) ? rdlane64(va, cur)
                                : (cur < 128) ? rdlane64(vb, cur - 64) : ~0ULL;
        __threadfence_block();

        if (pmin < ecur) {
            unsigned long long e = pmin;
            bool removed = false;
            #pragma unroll
            for (int t = 0; t < PENDK; ++t)
                if (!removed && pend[t] == e) { pend[t] = ~0ULL; removed = true; }
            pmin = ~0ULL;
            #pragma unroll
            for (int t = 0; t < PENDK; ++t) pmin = u64min(pmin, pend[t]);

            int re = (int)((e >> 11) & 0x3FF);
            int ce = (int)(e & 0x7FF);
            bool alive = (s_dead[re] == 0);
            if (alive) {
                if (lane == 0) {
                    rows_out[b * TT + m] = (float)re;
                    cols_out[b * TT + m] = (float)ce;
                    s_dead[re] = 1;
                }
                ++m;
            } else {
                float4 tc = *(const float4*)(tbox + (size_t)ce * 4);
                int idc = tlab[ce];
                unsigned long long best =
                    rescan_recompute(logits, pred, b, s_dead, ce, tc, idc, lane);
                bool placed = false;
                #pragma unroll
                for (int t = 0; t < PENDK; ++t)
                    if (!placed && pend[t] == ~0ULL) { pend[t] = best; placed = true; }
                pmin = u64min(pmin, best);
            }
        } else if (cur < 128) {
            int ccur = (int)(ecur & 0x7FF);
            float4 tc = *(const float4*)(tbox + (size_t)ccur * 4);
            int idc = tlab[ccur];
            unsigned long long best =
                rescan_recompute(logits, pred, b, s_dead, ccur, tc, idc, lane);
            bool placed = false;
            #pragma unroll
            for (int t = 0; t < PENDK; ++t)
                if (!placed && pend[t] == ~0ULL) { pend[t] = best; placed = true; }
            pmin = u64min(pmin, best);
            ++cur;
        }
    }
}

extern "C" void kernel_launch(void* const* d_in, const int* in_sizes, int n_in,
                              void* d_out, int out_size, void* d_ws, size_t ws_size,
                              hipStream_t stream) {
    const float* logits = (const float*)d_in[0];   // [16,900,91]
    const float* pred   = (const float*)d_in[1];   // [16,900,4]
    const int*   tlab   = (const int*)d_in[2];     // [16,100]
    const float* tbox   = (const float*)d_in[3];   // [16,100,4]

    float* out = (float*)d_out;
    float* cost = out;                              // 23,040,000
    float* rows = out + (size_t)BB * QQ * BT;       // 1600
    float* cols = rows + (size_t)BB * TT;           // 1600

    unsigned long long* slots = (unsigned long long*)d_ws;   // 768000 B, no init
    unsigned* done = (unsigned*)((char*)d_ws + DONE_OFF);    // 16 x 64 B, zeroed

    (void)hipMemsetAsync((char*)d_ws + DONE_OFF, 0, (size_t)BB * 64, stream);

    fused_kernel<<<GRID, NTHREADS, 0, stream>>>(
        logits, pred, tlab, tbox, cost, slots, done, rows, cols);
}